// Round 1
// 222.989 us; speedup vs baseline: 1.0740x; 1.0740x over previous
//
#include <hip/hip_runtime.h>
#include <hip/hip_bf16.h>

typedef __attribute__((ext_vector_type(8))) short short8;
typedef __attribute__((ext_vector_type(4))) float floatx4;
typedef __attribute__((ext_vector_type(4))) unsigned uint4v;
typedef __attribute__((ext_vector_type(4))) unsigned short ushort4v;

#define FDIM 512
#define CDIM 64
#define ODIM 256
#define TR   32      // rows per tile
#define XSF  516     // xs row stride in floats (512 + 4)
#define STS 40       // sT row stride (ushort)
#define MAXP 256
// row-dependent float offset (16B units) breaking cross-quad bank aliasing;
// wave-uniform per staging instruction so global_load_lds stays legal.
#define RSW(r) ((((r) >> 3) & 3) << 2)

// round-to-nearest-even fp32 -> bf16
__device__ __forceinline__ ushort f2bf(float f) {
    union { float f; unsigned u; } v; v.f = f;
    unsigned r = v.u + 0x7FFFu + ((v.u >> 16) & 1u);
    return (ushort)(r >> 16);
}
__device__ __forceinline__ float bf2f(unsigned hi16) {
    union { unsigned u; float f; } v; v.u = hi16 << 16; return v.f;
}

// async 16B/lane global -> LDS (lds dest = wave-uniform base + lane*16)
__device__ __forceinline__ void gld16(const float* g, float* lds_base) {
    __builtin_amdgcn_global_load_lds(
        (const __attribute__((address_space(1))) unsigned int*)(const void*)g,
        (__attribute__((address_space(3))) unsigned int*)(void*)lds_base,
        16, 0, 0);
}

// ---------------- WpT[c][f] = bf16(Wp[f][c]) (64 KB, L2/L3-resident) -------
__global__ __launch_bounds__(256) void kWpT(const float* __restrict__ Wp,
                                            ushort* __restrict__ WpT) {
    int g = blockIdx.x * 256 + threadIdx.x;   // 0..32767
    int f = g >> 6, c = g & 63;
    WpT[c * FDIM + f] = f2bf(Wp[f * CDIM + c]);
}

// ---------------- Fused: per 32-row tile, s=softmax(xWp+bp); M_p += s^T x --
// Grid = P blocks (<=256, 1 block/CU); block b handles tiles b, b+P, ...
// 512 threads = 8 waves. Double-buffered x staging: tile t+P prefetched via
// async global_load_lds into the alternate buffer while tile t computes.
// WpT A-fragments are tile-invariant -> hoisted to registers ONCE, so the
// K-loop has no global loads and never drains the prefetch vmcnt queue.
__global__ __launch_bounds__(512, 2) void kFused(
        const float* __restrict__ x, const ushort* __restrict__ WpT,
        const float* __restrict__ bp, ushort* __restrict__ part,
        float* __restrict__ cpart, int N, int nTiles, int P) {
    __shared__ float  xsf[2][TR * XSF + 16];  // 2 x 64.6 KB fp32 x tiles
    __shared__ ushort sT[CDIM][STS];          // 5.0 KB s^T [c][row]
    __shared__ float  red1[TR][4];
    __shared__ float  red2[TR][4];
    __shared__ float  cred[CDIM][2];

    const int t    = threadIdx.x;
    const int w    = t >> 6;        // 0..7
    const int lane = t & 63;
    const int l16  = lane & 15;
    const int q    = lane >> 4;
    const int ci   = w & 3;         // phase-1 c-tile (16 c)
    const int rg   = w >> 2;        // phase-1 row half (rows 16rg..16rg+15)

    // persistent M slice: c 0..63 (mt), f in [64w,64w+64) (nt) -> 64 VGPRs
    floatx4 acc[4][4];
#pragma unroll
    for (int mt = 0; mt < 4; ++mt)
#pragma unroll
        for (int nt = 0; nt < 4; ++nt) acc[mt][nt] = (floatx4){0.f, 0.f, 0.f, 0.f};
    float csp[4] = {0.f, 0.f, 0.f, 0.f};

    float bpv[4];
#pragma unroll
    for (int reg = 0; reg < 4; ++reg) bpv[reg] = bp[16 * ci + 4 * q + reg];

    // ---- hoist ALL phase-1 A fragments (WpT row 16ci+l16) : 64 VGPRs ----
    const ushort* wb = WpT + (size_t)(16 * ci + l16) * FDIM + q * 8;
    short8 af[4][4];
#pragma unroll
    for (int kb = 0; kb < 4; ++kb)
#pragma unroll
        for (int ki = 0; ki < 4; ++ki)
            af[kb][ki] = *(const short8*)(wb + kb * 128 + ki * 32);

    // stage x tile 'tile' into buffer xb: 32 rows x 2 KB, async, 8 chunks/wave
    auto stage = [&](int tile, float* xb) {
        const int row0s = tile * TR;
#pragma unroll
        for (int i = 0; i < 8; ++i) {
            const int c0 = w * 8 + i;          // 0..63
            const int r  = c0 >> 1;
            const int h  = c0 & 1;
            float* lb = xb + r * XSF + RSW(r) + h * 256;  // wave-uniform
            if (row0s + r < N) {
                const float* g = x + (size_t)(row0s + r) * FDIM + h * 256 + lane * 4;
                gld16(g, lb);
            } else {
                *(floatx4*)(lb + lane * 4) = (floatx4){0.f, 0.f, 0.f, 0.f};
            }
        }
    };

    // prologue: stage first tile, drain
    stage(blockIdx.x, xsf[0]);
    __syncthreads();

    int it = 0;
    for (int tile = blockIdx.x; tile < nTiles; tile += P, ++it) {
        float* xb = xsf[it & 1];
        // prefetch next tile into the alternate buffer (drains at end barrier)
        if (tile + P < nTiles) stage(tile + P, xsf[(it & 1) ^ 1]);

        const int row0 = tile * TR;

        // ---- phase 1: logitsT[c=16ci..+16][rows 16rg..+16], K=512 ----
        floatx4 acc1 = (floatx4){0.f, 0.f, 0.f, 0.f};
        const int prow = 16 * rg + l16;
        const float* xr = xb + prow * XSF + RSW(prow);  // this lane's B row
#pragma unroll
        for (int kb = 0; kb < 4; ++kb) {
#pragma unroll
            for (int ki = 0; ki < 4; ++ki) {
                const int off = kb * 128 + ki * 32 + q * 8;
                floatx4 u0 = *(const floatx4*)(xr + off);
                floatx4 u1 = *(const floatx4*)(xr + off + 4);
                short8 b;
                b[0] = (short)f2bf(u0[0]); b[1] = (short)f2bf(u0[1]);
                b[2] = (short)f2bf(u0[2]); b[3] = (short)f2bf(u0[3]);
                b[4] = (short)f2bf(u1[0]); b[5] = (short)f2bf(u1[1]);
                b[6] = (short)f2bf(u1[2]); b[7] = (short)f2bf(u1[3]);
                acc1 = __builtin_amdgcn_mfma_f32_16x16x32_bf16(af[kb][ki], b, acc1, 0, 0, 0);
            }
        }

        // ---- softmax over c per row; lane: c=16ci+4q+reg, row=16rg+l16 ----
        const int row = prow;
        float lg[4];
#pragma unroll
        for (int reg = 0; reg < 4; ++reg) lg[reg] = acc1[reg] + bpv[reg];
        float m = fmaxf(fmaxf(lg[0], lg[1]), fmaxf(lg[2], lg[3]));
        m = fmaxf(m, __shfl_xor(m, 16));
        m = fmaxf(m, __shfl_xor(m, 32));
        if (lane < 16) red1[16 * rg + lane][ci] = m;
        __syncthreads();
        const float rmax = fmaxf(fmaxf(red1[row][0], red1[row][1]),
                                 fmaxf(red1[row][2], red1[row][3]));
        float p = 0.f;
#pragma unroll
        for (int reg = 0; reg < 4; ++reg) {
            float e = __expf(lg[reg] - rmax);
            lg[reg] = e; p += e;
        }
        p += __shfl_xor(p, 16);
        p += __shfl_xor(p, 32);
        if (lane < 16) red2[16 * rg + lane][ci] = p;
        __syncthreads();
        const float rsi = 1.0f / (red2[row][0] + red2[row][1] +
                                  red2[row][2] + red2[row][3]);
        const bool valid = (row0 + row) < N;
#pragma unroll
        for (int reg = 0; reg < 4; ++reg) {
            float s = valid ? lg[reg] * rsi : 0.f;
            sT[16 * ci + 4 * q + reg][row] = f2bf(s);
            csp[reg] += s;
        }
        __syncthreads();   // sT ready; xb still intact

        // ---- phase 2: acc += s^T x over this tile (K=32 rows) ----
        short8 as_[4];
#pragma unroll
        for (int mt = 0; mt < 4; ++mt)
            as_[mt] = *(const short8*)&sT[16 * mt + l16][q * 8];
#pragma unroll
        for (int nt = 0; nt < 4; ++nt) {
            const int f = 64 * w + 16 * nt + l16;
            short8 b;
#pragma unroll
            for (int j = 0; j < 8; ++j)      // row 8q+j -> RSW = 4q
                b[j] = (short)f2bf(xb[(q * 8 + j) * XSF + 4 * q + f]);
#pragma unroll
            for (int mt = 0; mt < 4; ++mt)
                acc[mt][nt] = __builtin_amdgcn_mfma_f32_16x16x32_bf16(
                    as_[mt], b, acc[mt][nt], 0, 0, 0);
        }

        // end-of-iteration: all ph2 reads of xb done; prefetch vmcnt drained
        // (issued a full tile-compute ago -> no stall); next-iter writes safe.
        __syncthreads();
    }

    // ---- per-block colsum partial (fp32, no atomics) ----
#pragma unroll
    for (int reg = 0; reg < 4; ++reg) {
        float v = csp[reg];
        v += __shfl_xor(v, 1); v += __shfl_xor(v, 2);
        v += __shfl_xor(v, 4); v += __shfl_xor(v, 8);
        if (l16 == 0) cred[16 * ci + 4 * q + reg][rg] = v;
    }
    __syncthreads();
    if (t < 64) cpart[(size_t)blockIdx.x * CDIM + t] = cred[t][0] + cred[t][1];

    // ---- flush: acc -> xsf scratch (bf16) -> coalesced uint4 store ----
    ushort* xf = (ushort*)xsf;
#pragma unroll
    for (int mt = 0; mt < 4; ++mt)
#pragma unroll
        for (int nt = 0; nt < 4; ++nt)
#pragma unroll
            for (int reg = 0; reg < 4; ++reg)
                xf[(16 * mt + 4 * q + reg) * FDIM + 64 * w + 16 * nt + l16] =
                    f2bf(acc[mt][nt][reg]);
    __syncthreads();
    const uint4v* src = (const uint4v*)xf;
    uint4v* dst = (uint4v*)(part + (size_t)blockIdx.x * (CDIM * FDIM));
#pragma unroll
    for (int i = 0; i < 8; ++i)
        dst[i * 512 + t] = src[i * 512 + t];
}

// ---------------- stage-1 reduce: P partials -> 32 fp32 slices + colsum ----
// grid (64 c, 8 p-chunks), 512 threads = 4 p-subgroups x 128 f-threads.
// 8B ushort4 loads (vs 2B scalar before).
__global__ __launch_bounds__(512) void kR(const ushort* __restrict__ part,
                                          const float* __restrict__ cpart,
                                          float* __restrict__ colsum,
                                          float* __restrict__ Mp,
                                          int P, int pch) {
    __shared__ float ws8[8];
    const int c = blockIdx.x, pc = blockIdx.y, t = threadIdx.x;
    const int g  = t >> 7;            // p subgroup 0..3
    const int f0 = (t & 127) << 2;    // f base (0,4,...,508)
    const int p0 = pc * pch, p1 = min(p0 + pch, P);

    float s0 = 0.f, s1 = 0.f, s2 = 0.f, s3 = 0.f;
    for (int p = p0 + g; p < p1; p += 4) {
        const ushort4v v = *(const ushort4v*)(part + (size_t)p * (CDIM * FDIM)
                                              + (size_t)c * FDIM + f0);
        s0 += bf2f((unsigned)v[0]); s1 += bf2f((unsigned)v[1]);
        s2 += bf2f((unsigned)v[2]); s3 += bf2f((unsigned)v[3]);
    }
    floatx4 o = (floatx4){s0, s1, s2, s3};
    *(floatx4*)(Mp + (((size_t)(pc * 4 + g) * CDIM + c) * FDIM + f0)) = o;

    // colsum chunk (p = p0 + t)
    float cv = 0.f;
    {
        int p = p0 + t;
        if (p < p1) cv = cpart[(size_t)p * CDIM + c];
    }
    cv += __shfl_xor(cv, 1);  cv += __shfl_xor(cv, 2);
    cv += __shfl_xor(cv, 4);  cv += __shfl_xor(cv, 8);
    cv += __shfl_xor(cv, 16); cv += __shfl_xor(cv, 32);
    if ((t & 63) == 0) ws8[t >> 6] = cv;
    __syncthreads();
    if (t == 0) {
        float tot = 0.f;
#pragma unroll
        for (int i = 0; i < 8; ++i) tot += ws8[i];
        atomicAdd(colsum + c, tot);     // 512 adds total, uncontended
    }
}

// ---------------- epilogue: Mp -> M -> pooled -> out -----------------------
__global__ __launch_bounds__(512) void kC(const float* __restrict__ Mp,
                                          const float* __restrict__ colsum,
                                          const float* __restrict__ We,
                                          const float* __restrict__ be,
                                          const float* __restrict__ Wo,
                                          const float* __restrict__ bo,
                                          float* __restrict__ out) {
    __shared__ float Mrow[512];
    __shared__ float pooled[512];
    __shared__ float halves[2][256];
    const int c = blockIdx.x, t = threadIdx.x;

    float sum = 0.f;
#pragma unroll
    for (int pc = 0; pc < 32; ++pc)
        sum += Mp[((size_t)pc * CDIM + c) * FDIM + t];
    Mrow[t] = sum;
    __syncthreads();

    float a = colsum[c] * be[t];
#pragma unroll 16
    for (int k = 0; k < FDIM; ++k)
        a = fmaf(Mrow[k], We[(size_t)k * FDIM + t], a);
    pooled[t] = a;
    __syncthreads();

    const int o = t & 255, h = t >> 8;
    float b = 0.f;
#pragma unroll 16
    for (int kk = 0; kk < 256; ++kk) {
        int k = h * 256 + kk;
        b = fmaf(pooled[k], Wo[(size_t)k * ODIM + o], b);
    }
    halves[h][o] = b;
    __syncthreads();
    if (t < 256)
        out[(size_t)c * ODIM + t] = halves[0][t] + halves[1][t] + bo[t];
}

// ---------------------------------------------------------------------------
extern "C" void kernel_launch(void* const* d_in, const int* in_sizes, int n_in,
                              void* d_out, int out_size, void* d_ws, size_t ws_size,
                              hipStream_t stream) {
    const float* x  = (const float*)d_in[0];
    // d_in[1] edge_index, d_in[2] batch: unused by reference output
    const float* Wp = (const float*)d_in[3];
    const float* bp = (const float*)d_in[4];
    const float* We = (const float*)d_in[5];
    const float* be = (const float*)d_in[6];
    const float* Wo = (const float*)d_in[7];
    const float* bo = (const float*)d_in[8];
    float* out = (float*)d_out;

    const int N = in_sizes[0] / FDIM;          // 50000
    const int nTiles = (N + TR - 1) / TR;      // 1563

    // ws bytes:
    //   [0,       65536)  WpT bf16
    //   [65536,   65792)  colsum fp32
    //   [66560,   132096) cpart fp32 (P<=256)
    //   [266752, 4461056) Mp fp32 (32 x 64 x 512)
    //   [4461056, ...)    part bf16 (P x 64 KB)
    char*   wsb    = (char*)d_ws;
    ushort* WpT    = (ushort*)wsb;
    float*  colsum = (float*)(wsb + 65536);
    float*  cpart  = (float*)(wsb + 66560);
    float*  Mp     = (float*)(wsb + 266752);
    const size_t PART_OFF = 4461056;
    ushort* part   = (ushort*)(wsb + PART_OFF);

    size_t avail = (ws_size > PART_OFF + 65536) ? (ws_size - PART_OFF) / 65536 : 1;
    int P = (int)(avail < (size_t)MAXP ? avail : (size_t)MAXP);
    if (P > nTiles) P = nTiles;
    if (P < 1) P = 1;
    const int pch = (P + 7) / 8;

    hipMemsetAsync(colsum, 0, 256, stream);
    kWpT<<<128, 256, 0, stream>>>(Wp, WpT);
    kFused<<<P, 512, 0, stream>>>(x, WpT, bp, part, cpart, N, nTiles, P);
    kR<<<dim3(CDIM, 8), 512, 0, stream>>>(part, cpart, colsum, Mp, P, pch);
    kC<<<CDIM, 512, 0, stream>>>(Mp, colsum, We, be, Wo, bo, out);
}

// Round 2
// 220.580 us; speedup vs baseline: 1.0857x; 1.0109x over previous
//
#include <hip/hip_runtime.h>
#include <hip/hip_bf16.h>

typedef __attribute__((ext_vector_type(8))) short short8;
typedef __attribute__((ext_vector_type(4))) float floatx4;
typedef __attribute__((ext_vector_type(4))) unsigned uint4v;
typedef __attribute__((ext_vector_type(4))) unsigned short ushort4v;

#define FDIM 512
#define CDIM 64
#define ODIM 256
#define TR   32      // rows per tile
#define STS  40      // sT row stride (ushort)
#define MAXP 256

// round-to-nearest-even fp32 -> bf16
__device__ __forceinline__ ushort f2bf(float f) {
    union { float f; unsigned u; } v; v.f = f;
    unsigned r = v.u + 0x7FFFu + ((v.u >> 16) & 1u);
    return (ushort)(r >> 16);
}
__device__ __forceinline__ float bf2f(unsigned hi16) {
    union { unsigned u; float f; } v; v.u = hi16 << 16; return v.f;
}

// lgkm-only barrier: synchronizes LDS traffic WITHOUT draining vmcnt, so
// reg-staged global loads stay in flight across it (T4). The trailing empty
// asm is a compiler fence so loads can't migrate across the barrier.
#define LBAR() do {                                            \
    asm volatile("s_waitcnt lgkmcnt(0)" ::: "memory");         \
    __builtin_amdgcn_s_barrier();                              \
    asm volatile("" ::: "memory");                             \
} while (0)

// ---------------- Fused: per 32-row tile, s=softmax(xWp+bp); M_p += s^T x --
// Grid = P (<=256) blocks, 512 threads = 8 waves, 1 block/CU.
// Pipeline per iteration (reg-staged, T14):
//   issue 8x global_load_dwordx4 (tile t+1) -> 32 VGPRs   [no LDS dest]
//   phase1 + softmax + phase2 on bf16 LDS tile t           [lgkm-only barriers]
//   commit: counted-vmcnt wait -> f2bf -> ds_write (t+1 into alt buffer)
//   lgkm barrier
// x is converted fp32->bf16 exactly once per element; both MFMA phases read
// bf16 directly (phase1: ds_read_b128; phase2: 8x ds_read_u16).
// LDS bf16 tile is XOR-swizzled (f ^= (row&7)<<3, 16B granules) so phase-1's
// 16-rows-same-column ds_read_b128 pattern is conflict-free (T2).
__global__ __launch_bounds__(512, 2) void kFused(
        const float* __restrict__ x, const float* __restrict__ Wp,
        const float* __restrict__ bp, ushort* __restrict__ part,
        float* __restrict__ cpart, int N, int nTiles, int P) {
    __shared__ __align__(16) ushort xb2[2][TR * FDIM];   // 2 x 32 KB bf16 tiles
    __shared__ __align__(16) ushort sT[CDIM][STS];       // 5 KB s^T [c][row]
    __shared__ __align__(16) float  red1[TR][4];
    __shared__ __align__(16) float  red2[TR][4];
    __shared__ float  cred[CDIM][2];

    const int t    = threadIdx.x;
    const int w    = t >> 6;        // 0..7
    const int lane = t & 63;
    const int l16  = lane & 15;
    const int q    = lane >> 4;
    const int ci   = w & 3;         // phase-1 c-tile (16 c)
    const int rg   = w >> 2;        // phase-1 row half (rows 16rg..16rg+15)

    // persistent M slice: c 0..63 (mt), f in [64w,64w+64) (nt) -> 64 VGPRs
    floatx4 acc[4][4];
#pragma unroll
    for (int mt = 0; mt < 4; ++mt)
#pragma unroll
        for (int nt = 0; nt < 4; ++nt) acc[mt][nt] = (floatx4){0.f, 0.f, 0.f, 0.f};
    float csp[4] = {0.f, 0.f, 0.f, 0.f};

    float bpv[4];
#pragma unroll
    for (int reg = 0; reg < 4; ++reg) bpv[reg] = bp[16 * ci + 4 * q + reg];

    // ---- hoist phase-1 A fragments straight from Wp (one-time, L2-res) ----
    // af[kb][ki][j] = bf16(Wp[(kb*128+ki*32+q*8+j)][16ci+l16])
    short8 af[4][4];
    {
        const int c = 16 * ci + l16;
#pragma unroll
        for (int kb = 0; kb < 4; ++kb)
#pragma unroll
            for (int ki = 0; ki < 4; ++ki) {
                short8 a;
#pragma unroll
                for (int j = 0; j < 8; ++j)
                    a[j] = (short)f2bf(
                        Wp[(size_t)(kb * 128 + ki * 32 + q * 8 + j) * CDIM + c]);
                af[kb][ki] = a;
            }
    }

    // ---- reg staging: 8 x 16B per thread (64 KB fp32 tile) ----
    floatx4 st[8];
    auto issue = [&](int tile) {
        const int row0s = tile * TR;
#pragma unroll
        for (int i = 0; i < 8; ++i) {
            const int g  = i * 512 + t;     // float4 index in tile
            const int r  = g >> 7;          // row 0..31
            const int f4 = g & 127;         // float4 within row
            int rr = row0s + r;
            if (rr >= N) rr = N - 1;        // clamp: finite data; sT=0 masks it
            st[i] = *(const floatx4*)(x + (size_t)rr * FDIM + f4 * 4);
        }
    };
    auto commit = [&](ushort* xb) {         // counted-vmcnt wait happens here
#pragma unroll
        for (int i = 0; i < 8; ++i) {
            const int g  = i * 512 + t;
            const int r  = g >> 7;
            const int f0 = (g & 127) << 2;
            ushort4v v;
            v[0] = f2bf(st[i][0]); v[1] = f2bf(st[i][1]);
            v[2] = f2bf(st[i][2]); v[3] = f2bf(st[i][3]);
            *(ushort4v*)(xb + r * FDIM + (f0 ^ ((r & 7) << 3))) = v;
        }
    };

    // prologue: stage + convert first tile
    issue(blockIdx.x);
    commit(xb2[0]);
    LBAR();

    int cur = 0;
    for (int tile = blockIdx.x; tile < nTiles; tile += P) {
        const int  row0 = tile * TR;
        const bool pf   = (tile + P) < nTiles;
        if (pf) issue(tile + P);            // in flight across whole iteration

        const ushort* xr = &xb2[cur][0];

        // ---- phase 1: logitsT[c=16ci..+16][rows 16rg..+16], K=512 ----
        const int prow = 16 * rg + l16;
        const int sw   = (prow & 7) << 3;
        const ushort* xrow = xr + prow * FDIM;
        floatx4 a1a = (floatx4){0.f, 0.f, 0.f, 0.f};
        floatx4 a1b = (floatx4){0.f, 0.f, 0.f, 0.f};   // split dep chain
#pragma unroll
        for (int kb = 0; kb < 4; ++kb)
#pragma unroll
            for (int ki = 0; ki < 4; ++ki) {
                short8 b = *(const short8*)(xrow + ((kb * 128 + ki * 32 + q * 8) ^ sw));
                if (kb & 1)
                    a1b = __builtin_amdgcn_mfma_f32_16x16x32_bf16(af[kb][ki], b, a1b, 0, 0, 0);
                else
                    a1a = __builtin_amdgcn_mfma_f32_16x16x32_bf16(af[kb][ki], b, a1a, 0, 0, 0);
            }

        // ---- softmax over c per row; lane: c=16ci+4q+reg, row=16rg+l16 ----
        const int row = prow;
        float lg[4];
#pragma unroll
        for (int reg = 0; reg < 4; ++reg) lg[reg] = a1a[reg] + a1b[reg] + bpv[reg];
        float m = fmaxf(fmaxf(lg[0], lg[1]), fmaxf(lg[2], lg[3]));
        m = fmaxf(m, __shfl_xor(m, 16));
        m = fmaxf(m, __shfl_xor(m, 32));
        if (lane < 16) red1[16 * rg + lane][ci] = m;
        LBAR();
        const float rmax = fmaxf(fmaxf(red1[row][0], red1[row][1]),
                                 fmaxf(red1[row][2], red1[row][3]));
        float p = 0.f;
#pragma unroll
        for (int reg = 0; reg < 4; ++reg) {
            float e = __expf(lg[reg] - rmax);
            lg[reg] = e; p += e;
        }
        p += __shfl_xor(p, 16);
        p += __shfl_xor(p, 32);
        if (lane < 16) red2[16 * rg + lane][ci] = p;
        LBAR();
        const float rsi = 1.0f / (red2[row][0] + red2[row][1] +
                                  red2[row][2] + red2[row][3]);
        const bool valid = (row0 + row) < N;
#pragma unroll
        for (int reg = 0; reg < 4; ++reg) {
            float s = valid ? lg[reg] * rsi : 0.f;
            sT[16 * ci + 4 * q + reg][row] = f2bf(s);
            csp[reg] += s;
        }
        LBAR();   // sT ready

        // ---- phase 2: acc += s^T x over this tile (K=32 rows) ----
        short8 as_[4];
#pragma unroll
        for (int mt = 0; mt < 4; ++mt)
            as_[mt] = *(const short8*)&sT[16 * mt + l16][q * 8];
#pragma unroll
        for (int nt = 0; nt < 4; ++nt) {
            const int fc = 64 * w + 16 * nt + l16;
            short8 b;
#pragma unroll
            for (int j = 0; j < 8; ++j)      // row q*8+j -> row&7 == j
                b[j] = (short)xr[(q * 8 + j) * FDIM + (fc ^ (j << 3))];
#pragma unroll
            for (int mt = 0; mt < 4; ++mt)
                acc[mt][nt] = __builtin_amdgcn_mfma_f32_16x16x32_bf16(
                    as_[mt], b, acc[mt][nt], 0, 0, 0);
        }

        if (pf) commit(xb2[cur ^ 1]);       // waits staged regs (counted vmcnt)
        LBAR();                             // alt buffer ready for next iter
        cur ^= 1;
    }

    // ---- per-block colsum partial (fp32, no atomics) ----
#pragma unroll
    for (int reg = 0; reg < 4; ++reg) {
        float v = csp[reg];
        v += __shfl_xor(v, 1); v += __shfl_xor(v, 2);
        v += __shfl_xor(v, 4); v += __shfl_xor(v, 8);
        if (l16 == 0) cred[16 * ci + 4 * q + reg][rg] = v;
    }
    __syncthreads();
    if (t < 64) cpart[(size_t)blockIdx.x * CDIM + t] = cred[t][0] + cred[t][1];

    // ---- flush: acc -> xb2 scratch (bf16) -> coalesced uint4 store ----
    ushort* xf = &xb2[0][0];                 // 64 KB scratch
#pragma unroll
    for (int mt = 0; mt < 4; ++mt)
#pragma unroll
        for (int nt = 0; nt < 4; ++nt)
#pragma unroll
            for (int reg = 0; reg < 4; ++reg)
                xf[(16 * mt + 4 * q + reg) * FDIM + 64 * w + 16 * nt + l16] =
                    f2bf(acc[mt][nt][reg]);
    __syncthreads();
    const uint4v* src = (const uint4v*)xf;
    uint4v* dst = (uint4v*)(part + (size_t)blockIdx.x * (CDIM * FDIM));
#pragma unroll
    for (int i = 0; i < 8; ++i)
        dst[i * 512 + t] = src[i * 512 + t];
}

// ---------------- stage-1 reduce: P partials -> 32 fp32 slices + colsum ----
// grid (64 c, 8 p-chunks), 512 threads = 4 p-subgroups x 128 f-threads.
__global__ __launch_bounds__(512) void kR(const ushort* __restrict__ part,
                                          const float* __restrict__ cpart,
                                          float* __restrict__ colsum,
                                          float* __restrict__ Mp,
                                          int P, int pch) {
    __shared__ float ws8[8];
    const int c = blockIdx.x, pc = blockIdx.y, t = threadIdx.x;
    const int g  = t >> 7;            // p subgroup 0..3
    const int f0 = (t & 127) << 2;    // f base (0,4,...,508)
    const int p0 = pc * pch, p1 = min(p0 + pch, P);

    float s0 = 0.f, s1 = 0.f, s2 = 0.f, s3 = 0.f;
    for (int p = p0 + g; p < p1; p += 4) {
        const ushort4v v = *(const ushort4v*)(part + (size_t)p * (CDIM * FDIM)
                                              + (size_t)c * FDIM + f0);
        s0 += bf2f((unsigned)v[0]); s1 += bf2f((unsigned)v[1]);
        s2 += bf2f((unsigned)v[2]); s3 += bf2f((unsigned)v[3]);
    }
    floatx4 o = (floatx4){s0, s1, s2, s3};
    *(floatx4*)(Mp + (((size_t)(pc * 4 + g) * CDIM + c) * FDIM + f0)) = o;

    // colsum chunk (p = p0 + t)
    float cv = 0.f;
    {
        int p = p0 + t;
        if (p < p1) cv = cpart[(size_t)p * CDIM + c];
    }
    cv += __shfl_xor(cv, 1);  cv += __shfl_xor(cv, 2);
    cv += __shfl_xor(cv, 4);  cv += __shfl_xor(cv, 8);
    cv += __shfl_xor(cv, 16); cv += __shfl_xor(cv, 32);
    if ((t & 63) == 0) ws8[t >> 6] = cv;
    __syncthreads();
    if (t == 0) {
        float tot = 0.f;
#pragma unroll
        for (int i = 0; i < 8; ++i) tot += ws8[i];
        atomicAdd(colsum + c, tot);     // 512 adds total, uncontended
    }
}

// ---------------- epilogue: Mp -> M -> pooled -> out -----------------------
__global__ __launch_bounds__(512) void kC(const float* __restrict__ Mp,
                                          const float* __restrict__ colsum,
                                          const float* __restrict__ We,
                                          const float* __restrict__ be,
                                          const float* __restrict__ Wo,
                                          const float* __restrict__ bo,
                                          float* __restrict__ out) {
    __shared__ float Mrow[512];
    __shared__ float pooled[512];
    __shared__ float halves[2][256];
    const int c = blockIdx.x, t = threadIdx.x;

    float sum = 0.f;
#pragma unroll
    for (int pc = 0; pc < 32; ++pc)
        sum += Mp[((size_t)pc * CDIM + c) * FDIM + t];
    Mrow[t] = sum;
    __syncthreads();

    float a = colsum[c] * be[t];
#pragma unroll 16
    for (int k = 0; k < FDIM; ++k)
        a = fmaf(Mrow[k], We[(size_t)k * FDIM + t], a);
    pooled[t] = a;
    __syncthreads();

    const int o = t & 255, h = t >> 8;
    float b = 0.f;
#pragma unroll 16
    for (int kk = 0; kk < 256; ++kk) {
        int k = h * 256 + kk;
        b = fmaf(pooled[k], Wo[(size_t)k * ODIM + o], b);
    }
    halves[h][o] = b;
    __syncthreads();
    if (t < 256)
        out[(size_t)c * ODIM + t] = halves[0][t] + halves[1][t] + bo[t];
}

// ---------------------------------------------------------------------------
extern "C" void kernel_launch(void* const* d_in, const int* in_sizes, int n_in,
                              void* d_out, int out_size, void* d_ws, size_t ws_size,
                              hipStream_t stream) {
    const float* x  = (const float*)d_in[0];
    // d_in[1] edge_index, d_in[2] batch: unused by reference output
    const float* Wp = (const float*)d_in[3];
    const float* bp = (const float*)d_in[4];
    const float* We = (const float*)d_in[5];
    const float* be = (const float*)d_in[6];
    const float* Wo = (const float*)d_in[7];
    const float* bo = (const float*)d_in[8];
    float* out = (float*)d_out;

    const int N = in_sizes[0] / FDIM;          // 50000
    const int nTiles = (N + TR - 1) / TR;      // 1563

    // ws bytes:
    //   [0,       256)      colsum fp32
    //   [1024,    66560)    cpart fp32 (P<=256)
    //   [66560,   4260864)  Mp fp32 (32 x 64 x 512)
    //   [4260864, ...)      part bf16 (P x 64 KB)
    char*   wsb    = (char*)d_ws;
    float*  colsum = (float*)wsb;
    float*  cpart  = (float*)(wsb + 1024);
    float*  Mp     = (float*)(wsb + 66560);
    const size_t PART_OFF = 4260864;
    ushort* part   = (ushort*)(wsb + PART_OFF);

    size_t avail = (ws_size > PART_OFF + 65536) ? (ws_size - PART_OFF) / 65536 : 1;
    int P = (int)(avail < (size_t)MAXP ? avail : (size_t)MAXP);
    if (P > nTiles) P = nTiles;
    if (P < 1) P = 1;
    const int pch = (P + 7) / 8;

    hipMemsetAsync(colsum, 0, 256, stream);
    kFused<<<P, 512, 0, stream>>>(x, Wp, bp, part, cpart, N, nTiles, P);
    kR<<<dim3(CDIM, 8), 512, 0, stream>>>(part, cpart, colsum, Mp, P, pch);
    kC<<<CDIM, 512, 0, stream>>>(Mp, colsum, We, be, Wo, bo, out);
}